// Round 6
// baseline (386494.165 us; speedup 1.0000x reference)
//
#include <hip/hip_runtime.h>
#include <math.h>

// Problem constants
#define NN 1024
#define MM 64
#define CC 512
#define LL 64
#define TT 8192
#define EPSF 1e-16f
#define MPAD 1027   // LDS leading-dim pad: bank = (3c + row) % 32 -> conflict-free both ways

// Flat output offsets (return order: seq_out, ww_h, rw_h, a_h, r_h)
#define OFF_SEQ 0
#define OFF_WW  (TT*LL)
#define OFF_RW  (OFF_WW + TT*NN)
#define OFF_A   (OFF_RW + TT*NN)
#define OFF_R   (OFF_A + TT*MM)

__device__ __forceinline__ float sigmoid_f(float x) { return 1.0f / (1.0f + __expf(-x)); }
__device__ __forceinline__ float softplus_f(float x) { return (x > 15.0f) ? x : __logf(1.0f + __expf(x)); }
__device__ __forceinline__ float tanh_f(float x) { float e = __expf(2.0f * x); return 1.0f - 2.0f / (e + 1.0f); }
__device__ __forceinline__ float pow_f(float b, float g) { return __expf(g * __logf(b)); }  // b >= 0
__device__ __forceinline__ int bitrev4(int l) {
    return ((l & 1) << 3) | ((l & 2) << 1) | ((l & 4) >> 1) | ((l & 8) >> 3);
}

// Kernel 1: pre[t][j] = sum_i seq[t][i] * Wc[i][j] + bc[j]
__global__ void pre_kernel(const float* __restrict__ seq, const float* __restrict__ Wc,
                           const float* __restrict__ bc, float* __restrict__ pre) {
    int gid = blockIdx.x * blockDim.x + threadIdx.x;
    int t = gid >> 9;
    int j = gid & 511;
    if (t >= TT) return;
    const float* s = seq + t * LL;
    float acc = bc[j];
    #pragma unroll 8
    for (int i = 0; i < LL; ++i) acc += s[i] * Wc[i * CC + j];
    pre[gid] = acc;
}

// Persistent single workgroup. M cols 0-31 live in LDS (m_lds[32][1027]); cols 32-63
// in d_ws private float4 (loaded phase-E, held regs through phase-H, stored phase-G).
// Peak live regs ~58 < 64 arch VGPRs => no AGPR-copy tax (round-5 held M in 95+ live
// values at a 64-VGPR budget; excess VALU issue matched AGPR ping-pong).
__global__ __launch_bounds__(1024)
void ntm_kernel(
    const float* __restrict__ pre,  // [TT][CC]
    const float* __restrict__ Wc,   // [128][512]
    const float* __restrict__ Wr,   // [512][70]
    const float* __restrict__ br,   // [70]
    const float* __restrict__ Ww,   // [512][198]
    const float* __restrict__ bw,   // [198]
    const float* __restrict__ Wo,   // [64][64]
    const float* __restrict__ bo,   // [64]
    float* __restrict__ out,
    float4* __restrict__ ws_m)      // [8][1024] private M cols 32..63
{
    __shared__ float m_lds[32 * MPAD];                // M cols 0..31, [c][row]
    __shared__ __align__(16) float sh_part[1088];
    __shared__ __align__(16) float sh_h[CC];
    __shared__ __align__(16) float sh_kw[MM];
    __shared__ __align__(16) float sh_kr[MM];
    __shared__ __align__(16) float sh_e[MM];
    __shared__ __align__(16) float sh_a[MM];
    __shared__ __align__(16) float sh_scal[16];
    __shared__ __align__(16) float sh_evbuf[NN];
    __shared__ __align__(16) float sh_wpbuf[NN];
    __shared__ __align__(16) float sh_wsh[NN];        // unnormalized wshR for col-parallel r
    __shared__ __align__(16) float red[4][16];
    __shared__ __align__(16) float wmat[16][MM];      // r_n partials: [g][c<32] and [wv][c>=32]
    __shared__ __align__(16) float sh_r[MM];
    __shared__ __align__(16) float sh_bo[LL];
    __shared__ __align__(16) float sh_bw[200];
    __shared__ __align__(16) float sh_br[72];

    const int tid  = threadIdx.x;
    const int lane = tid & 63;
    const int wv   = tid >> 6;

    // ---- init ----
    for (int i = tid; i < 32 * MPAD; i += NN) m_lds[i] = 1e-6f;
    if (tid < LL)  sh_bo[tid] = bo[tid];
    if (tid < 198) sh_bw[tid] = bw[tid];
    if (tid < 70)  sh_br[tid] = br[tid];
    if (tid < MM)  sh_r[tid] = 1e-6f;
    float4 mh[8];
    #pragma unroll
    for (int k = 0; k < 8; ++k) {
        mh[k] = make_float4(1e-6f, 1e-6f, 1e-6f, 1e-6f);
        ws_m[k * NN + tid] = mh[k];
    }
    float rown = sqrtf(64.0f * 1e-12f);
    float wwprev = (tid == NN / 2) ? 1.0f : 0.0f;
    float rwprev = wwprev;
    float pre_reg = (tid < CC) ? pre[tid] : 0.0f;     // held-register pre prefetch
    __syncthreads();

    for (int t = 0; t < TT; ++t) {
        // ===== A: h-partials  part[tid] = (r-half) @ Wc2 =====
        {
            int j = tid & 511, half = tid >> 9;
            const float* wc2 = Wc + (64 + half * 32) * CC + j;
            const float4* r4p = (const float4*)(sh_r + half * 32);
            float a0 = 0.0f, a1 = 0.0f;
            #pragma unroll
            for (int i4 = 0; i4 < 8; ++i4) {
                float4 r4 = r4p[i4];
                const float* w = wc2 + (i4 * 4) * CC;
                a0 += r4.x * w[0] + r4.y * w[CC];
                a1 += r4.z * w[2 * CC] + r4.w * w[3 * CC];
            }
            sh_part[tid] = a0 + a1;
        }
        __syncthreads();  // 1
        // ===== B: h = tanh(pre + parts); prefetch pre[t+1] into register =====
        if (tid < CC) {
            float v = pre_reg + sh_part[tid] + sh_part[tid + CC];
            sh_h[tid] = tanh_f(v);
            int tn = (t + 1 < TT) ? (t + 1) : t;
            pre_reg = pre[tn * CC + tid];             // consumed next step: fully hidden
        }
        __syncthreads();  // 2
        // ===== C: ow/orr partials (536 threads, 2 row-halves) =====
        if (tid < 536) {
            int q = (tid < 268) ? 0 : 1;
            int c = tid - q * 268;
            const float* Wp; int ncol, col;
            if (c < 198) { Wp = Ww; ncol = 198; col = c; }
            else         { Wp = Wr; ncol = 70;  col = c - 198; }
            const float* wptr = Wp + (q * 256) * ncol + col;
            const float4* h4 = (const float4*)(sh_h + q * 256);
            float a0 = 0.0f, a1 = 0.0f;
            #pragma unroll 8
            for (int i4 = 0; i4 < 64; ++i4) {
                float4 h = h4[i4];
                const float* w = wptr + (i4 * 4) * ncol;
                a0 += h.x * w[0] + h.y * w[ncol];
                a1 += h.z * w[2 * ncol] + h.w * w[3 * ncol];
            }
            sh_part[tid] = a0 + a1;
        }
        __syncthreads();  // 3
        // ===== D: head transforms (ow computed inline from parts; bias fold merged) =====
        #define OWV(c) (sh_part[(c)] + sh_part[268 + (c)] + ((c) < 198 ? sh_bw[(c)] : sh_br[(c) - 198]))
        if (wv == 0) {
            float v = tanh_f(OWV(lane));
            sh_kw[lane] = v;
            float s2 = v * v;
            #pragma unroll
            for (int m = 1; m < 64; m <<= 1) s2 += __shfl_xor(s2, m, 64);
            if (lane == 0) sh_scal[6] = sqrtf(s2);
        } else if (wv == 1) {
            float v = tanh_f(OWV(198 + lane));
            sh_kr[lane] = v;
            float s2 = v * v;
            #pragma unroll
            for (int m = 1; m < 64; m <<= 1) s2 += __shfl_xor(s2, m, 64);
            if (lane == 0) sh_scal[14] = sqrtf(s2);
        } else if (wv == 2) {
            sh_e[lane] = sigmoid_f(OWV(70 + lane));
        } else if (wv == 3) {
            float v = tanh_f(OWV(134 + lane));
            sh_a[lane] = v;
            out[OFF_A + t * MM + lane] = v;
        } else if (wv == 4) {
            if (lane == 0) {
                sh_scal[0] = softplus_f(OWV(64));
                sh_scal[1] = sigmoid_f(OWV(65));
                float x0 = OWV(66), x1 = OWV(67), x2 = OWV(68);
                float mx = fmaxf(x0, fmaxf(x1, x2));
                float e0 = __expf(x0 - mx), e1 = __expf(x1 - mx), e2 = __expf(x2 - mx);
                float ss = e0 + e1 + e2;
                sh_scal[2] = e0 / ss; sh_scal[3] = e1 / ss; sh_scal[4] = e2 / ss;
                sh_scal[5] = 1.0f + softplus_f(OWV(69));
            }
        } else if (wv == 5) {
            if (lane == 0) {
                sh_scal[8] = softplus_f(OWV(198 + 64));
                sh_scal[9] = sigmoid_f(OWV(198 + 65));
                float x0 = OWV(198 + 66), x1 = OWV(198 + 67), x2 = OWV(198 + 68);
                float mx = fmaxf(x0, fmaxf(x1, x2));
                float e0 = __expf(x0 - mx), e1 = __expf(x1 - mx), e2 = __expf(x2 - mx);
                float ss = e0 + e1 + e2;
                sh_scal[10] = e0 / ss; sh_scal[11] = e1 / ss; sh_scal[12] = e2 / ss;
                sh_scal[13] = 1.0f + softplus_f(OWV(198 + 69));
            }
        }
        #undef OWV
        __syncthreads();  // 4

        // ===== E: write-head dot + ev =====
        float betaW = sh_scal[0], gW = sh_scal[1];
        float s0W = sh_scal[2], s1W = sh_scal[3], s2W = sh_scal[4];
        float gamW = sh_scal[5], knW = sh_scal[6];
        {
            #pragma unroll
            for (int k = 0; k < 8; ++k) mh[k] = ws_m[k * NN + tid];   // issue early
            const float4* kw4 = (const float4*)sh_kw;
            float d0 = 0.0f, d1 = 0.0f, d2 = 0.0f, d3 = 0.0f;
            #pragma unroll
            for (int c4 = 0; c4 < 8; ++c4) {
                float4 k = kw4[c4];
                const float* mp = m_lds + (4 * c4) * MPAD + tid;
                d0 += mp[0] * k.x;        d1 += mp[MPAD] * k.y;
                d2 += mp[2 * MPAD] * k.z; d3 += mp[3 * MPAD] * k.w;
            }
            #pragma unroll
            for (int k8 = 0; k8 < 8; ++k8) {
                float4 k = kw4[8 + k8];
                d0 += mh[k8].x * k.x; d1 += mh[k8].y * k.y;
                d2 += mh[k8].z * k.z; d3 += mh[k8].w * k.w;
            }
            float dot = (d0 + d1) + (d2 + d3);
            float sim = dot / (rown * knW + EPSF);
            float ev = __expf(betaW * sim);
            sh_evbuf[tid] = ev;
            sh_wpbuf[tid] = wwprev;
            float s = ev;
            #pragma unroll
            for (int m = 1; m < 64; m <<= 1) s += __shfl_xor(s, m, 64);
            if (lane == 0) red[0][wv] = s;
        }
        __syncthreads();  // 5
        // ===== F: conv + sharpen (write head) =====
        float wshW;
        {
            const float4* rp = (const float4*)red[0];
            float Sev = 0.0f;
            #pragma unroll
            for (int w4 = 0; w4 < 4; ++w4) { float4 p = rp[w4]; Sev += p.x + p.y + p.z + p.w; }
            int tm1 = (tid + NN - 1) & (NN - 1), tp1 = (tid + 1) & (NN - 1);
            float cEV = s0W * sh_evbuf[tm1] + s1W * sh_evbuf[tid] + s2W * sh_evbuf[tp1];
            float cWP = s0W * sh_wpbuf[tm1] + s1W * sh_wpbuf[tid] + s2W * sh_wpbuf[tp1];
            float ws = (gW / Sev) * cEV + (1.0f - gW) * cWP;
            wshW = pow_f(ws, gamW);
            float s = wshW;
            #pragma unroll
            for (int m = 1; m < 64; m <<= 1) s += __shfl_xor(s, m, 64);
            if (lane == 0) red[1][wv] = s;
        }
        __syncthreads();  // 6
        // ===== G: normalize wwn; M update fused with read-head dot =====
        float betaR = sh_scal[8], gR = sh_scal[9];
        float s0R = sh_scal[10], s1R = sh_scal[11], s2R = sh_scal[12];
        float gamR = sh_scal[13], knR = sh_scal[14];
        {
            const float4* rp = (const float4*)red[1];
            float Swsh = 0.0f;
            #pragma unroll
            for (int w4 = 0; w4 < 4; ++w4) { float4 p = rp[w4]; Swsh += p.x + p.y + p.z + p.w; }
            float wwn = wshW / (Swsh + EPSF);
            out[OFF_WW + t * NN + tid] = wwn;
            wwprev = wwn;
            const float4* e4 = (const float4*)sh_e;
            const float4* a4 = (const float4*)sh_a;
            const float4* kr4 = (const float4*)sh_kr;
            float n0 = 0.0f, n1 = 0.0f, n2 = 0.0f, n3 = 0.0f;
            float r0 = 0.0f, r1 = 0.0f, r2 = 0.0f, r3 = 0.0f;
            #pragma unroll
            for (int c4 = 0; c4 < 8; ++c4) {
                float4 e = e4[c4], a = a4[c4], kq = kr4[c4];
                float* mp = m_lds + (4 * c4) * MPAD + tid;
                float m0 = mp[0];        m0 = m0 * (1.0f - wwn * e.x) + wwn * a.x; mp[0] = m0;        n0 += m0 * m0; r0 += m0 * kq.x;
                float m1 = mp[MPAD];     m1 = m1 * (1.0f - wwn * e.y) + wwn * a.y; mp[MPAD] = m1;     n1 += m1 * m1; r1 += m1 * kq.y;
                float m2 = mp[2 * MPAD]; m2 = m2 * (1.0f - wwn * e.z) + wwn * a.z; mp[2 * MPAD] = m2; n2 += m2 * m2; r2 += m2 * kq.z;
                float m3 = mp[3 * MPAD]; m3 = m3 * (1.0f - wwn * e.w) + wwn * a.w; mp[3 * MPAD] = m3; n3 += m3 * m3; r3 += m3 * kq.w;
            }
            #pragma unroll
            for (int k = 0; k < 8; ++k) {
                float4 e = e4[8 + k], a = a4[8 + k], kq = kr4[8 + k];
                float4 m = mh[k];
                m.x = m.x * (1.0f - wwn * e.x) + wwn * a.x;
                m.y = m.y * (1.0f - wwn * e.y) + wwn * a.y;
                m.z = m.z * (1.0f - wwn * e.z) + wwn * a.z;
                m.w = m.w * (1.0f - wwn * e.w) + wwn * a.w;
                mh[k] = m;
                ws_m[k * NN + tid] = m;
                n0 += m.x * m.x; n1 += m.y * m.y; n2 += m.z * m.z; n3 += m.w * m.w;
                r0 += m.x * kq.x; r1 += m.y * kq.y; r2 += m.z * kq.z; r3 += m.w * kq.w;
            }
            rown = sqrtf((n0 + n1) + (n2 + n3));
            float dotR = (r0 + r1) + (r2 + r3);
            float sim = dotR / (rown * knR + EPSF);
            float ev = __expf(betaR * sim);
            sh_evbuf[tid] = ev;
            sh_wpbuf[tid] = rwprev;
            float s = ev;
            #pragma unroll
            for (int m = 1; m < 64; m <<= 1) s += __shfl_xor(s, m, 64);
            if (lane == 0) red[2][wv] = s;
        }
        __syncthreads();  // 7
        // ===== H: conv + sharpen (read head); transpose partials for cols 32-63 =====
        float wshR;
        {
            const float4* rp = (const float4*)red[2];
            float Sev = 0.0f;
            #pragma unroll
            for (int w4 = 0; w4 < 4; ++w4) { float4 p = rp[w4]; Sev += p.x + p.y + p.z + p.w; }
            int tm1 = (tid + NN - 1) & (NN - 1), tp1 = (tid + 1) & (NN - 1);
            float cEV = s0R * sh_evbuf[tm1] + s1R * sh_evbuf[tid] + s2R * sh_evbuf[tp1];
            float cWP = s0R * sh_wpbuf[tm1] + s1R * sh_wpbuf[tid] + s2R * sh_wpbuf[tp1];
            float ws = (gR / Sev) * cEV + (1.0f - gR) * cWP;
            wshR = pow_f(ws, gamR);
            sh_wsh[tid] = wshR;
            float s = wshR;
            #pragma unroll
            for (int m = 1; m < 64; m <<= 1) s += __shfl_xor(s, m, 64);
            if (lane == 0) red[3][wv] = s;
            // transpose-reduce for cols 32..63 (mh in regs), 2 chunks of 16
            #pragma unroll
            for (int chunk = 0; chunk < 2; ++chunk) {
                float v[16];
                #pragma unroll
                for (int k = 0; k < 4; ++k) {
                    float4 m = mh[chunk * 4 + k];
                    v[4*k]   = wshR * m.x; v[4*k+1] = wshR * m.y;
                    v[4*k+2] = wshR * m.z; v[4*k+3] = wshR * m.w;
                }
                #pragma unroll
                for (int st = 0; st < 4; ++st) {
                    const int m = 1 << st;
                    const int hs = 8 >> st;
                    bool hi = (lane & m) != 0;
                    #pragma unroll
                    for (int i = 0; i < 8; ++i) {
                        if (i < hs) {
                            float send = hi ? v[i] : v[i + hs];
                            float recv = __shfl_xor(send, m, 64);
                            float keep = hi ? v[i + hs] : v[i];
                            v[i] = keep + recv;
                        }
                    }
                }
                float v0 = v[0];
                v0 += __shfl_xor(v0, 16, 64);
                v0 += __shfl_xor(v0, 32, 64);
                if (lane < 16) wmat[wv][32 + chunk * 16 + bitrev4(lane)] = v0;
            }
        }
        __syncthreads();  // 8
        // ===== I: normalize rwn + column-parallel r partials for cols 0-31 =====
        float inv;
        {
            const float4* rp = (const float4*)red[3];
            float Swsh = 0.0f;
            #pragma unroll
            for (int w4 = 0; w4 < 4; ++w4) { float4 p = rp[w4]; Swsh += p.x + p.y + p.z + p.w; }
            inv = 1.0f / (Swsh + EPSF);
            float rwn = wshR * inv;
            out[OFF_RW + t * NN + tid] = rwn;
            rwprev = rwn;
            if (tid < 512) {
                int c = tid & 31, g = tid >> 5;
                const float* mp = m_lds + c * MPAD + g * 64;
                const float* wp = sh_wsh + g * 64;
                float a0 = 0.0f, a1 = 0.0f, a2 = 0.0f, a3 = 0.0f;
                #pragma unroll
                for (int i = 0; i < 64; i += 4) {
                    a0 += wp[i] * mp[i];         a1 += wp[i + 1] * mp[i + 1];
                    a2 += wp[i + 2] * mp[i + 2]; a3 += wp[i + 3] * mp[i + 3];
                }
                wmat[g][c] = (a0 + a1) + (a2 + a3);
            }
        }
        __syncthreads();  // 9
        // ===== J: finalize r =====
        if (tid < MM) {
            float rv = 0.0f;
            #pragma unroll
            for (int w = 0; w < 16; ++w) rv += wmat[w][tid];
            rv *= inv;
            sh_r[tid] = rv;
            out[OFF_R + t * MM + tid] = rv;
        }
        __syncthreads();  // 10
        // ===== K: output projection (off critical path; Wo streamed from L2) =====
        if (tid < LL) {
            const float4* r4p = (const float4*)sh_r;
            float a0 = 0.0f, a1 = 0.0f;
            #pragma unroll
            for (int i4 = 0; i4 < 16; ++i4) {
                float4 r = r4p[i4];
                const float* w = Wo + (4 * i4) * LL + tid;
                a0 += r.x * w[0]      + r.y * w[LL];
                a1 += r.z * w[2 * LL] + r.w * w[3 * LL];
            }
            float acc = sh_bo[tid] + a0 + a1;
            out[OFF_SEQ + t * LL + tid] = fminf(fmaxf(acc, 0.0f), 1.0f);
        }
        // no barrier: next phase A reads only sh_r (stable until next J)
    }
}

extern "C" void kernel_launch(void* const* d_in, const int* in_sizes, int n_in,
                              void* d_out, int out_size, void* d_ws, size_t ws_size,
                              hipStream_t stream) {
    const float* seq = (const float*)d_in[0];
    const float* Wc  = (const float*)d_in[1];
    const float* bc  = (const float*)d_in[2];
    const float* Wr  = (const float*)d_in[3];
    const float* br  = (const float*)d_in[4];
    const float* Ww  = (const float*)d_in[5];
    const float* bw  = (const float*)d_in[6];
    const float* Wo  = (const float*)d_in[7];
    const float* bo  = (const float*)d_in[8];
    float* out = (float*)d_out;
    float* pre = (float*)d_ws;                         // 16 MB
    float4* ws_m = (float4*)((float*)d_ws + TT * CC);  // +128 KB private M cols 32..63

    pre_kernel<<<(TT * CC) / 256, 256, 0, stream>>>(seq, Wc, bc, pre);
    ntm_kernel<<<1, 1024, 0, stream>>>(pre, Wc, Wr, br, Ww, bw, Wo, bo, out, ws_m);
}

// Round 7
// 174342.969 us; speedup vs baseline: 2.2169x; 2.2169x over previous
//
#include <hip/hip_runtime.h>
#include <math.h>

// Problem constants
#define NN 1024
#define MM 64
#define CC 512
#define LL 64
#define TT 8192
#define EPSF 1e-16f

// Flat output offsets (return order: seq_out, ww_h, rw_h, a_h, r_h)
#define OFF_SEQ 0
#define OFF_WW  (TT*LL)
#define OFF_RW  (OFF_WW + TT*NN)
#define OFF_A   (OFF_RW + TT*NN)
#define OFF_R   (OFF_A + TT*MM)

// d_ws float offsets
#define WSF_PRE   0
#define WSF_M     (TT*CC)              // 8*1024 float4 = 32768 floats (M cols 32..63)
#define WSF_WCAT  (WSF_M + 32768)      // 512*272 packed [Ww | Wr | 0pad]

__device__ __forceinline__ float sigmoid_f(float x) { return 1.0f / (1.0f + __expf(-x)); }
__device__ __forceinline__ float softplus_f(float x) { return (x > 15.0f) ? x : __logf(1.0f + __expf(x)); }
__device__ __forceinline__ float tanh_f(float x) { float e = __expf(2.0f * x); return 1.0f - 2.0f / (e + 1.0f); }
__device__ __forceinline__ float pow_f(float b, float g) { return __expf(g * __logf(b)); }  // b >= 0
__device__ __forceinline__ int bitrev4(int l) {
    return ((l & 1) << 3) | ((l & 2) << 1) | ((l & 4) >> 1) | ((l & 8) >> 3);
}

// Kernel 1: pre[t][j] = sum_i seq[t][i] * Wc[i][j] + bc[j]
__global__ void pre_kernel(const float* __restrict__ seq, const float* __restrict__ Wc,
                           const float* __restrict__ bc, float* __restrict__ pre) {
    int gid = blockIdx.x * blockDim.x + threadIdx.x;
    int t = gid >> 9;
    int j = gid & 511;
    if (t >= TT) return;
    const float* s = seq + t * LL;
    float acc = bc[j];
    #pragma unroll 8
    for (int i = 0; i < LL; ++i) acc += s[i] * Wc[i * CC + j];
    pre[gid] = acc;
}

// Kernel 1b: Wcat[512][272] = [Ww (198 cols) | Wr (70 cols) | 4 zero cols]
// -> phase C reads one matrix with float4-aligned column groups.
__global__ void pack_kernel(const float* __restrict__ Ww, const float* __restrict__ Wr,
                            float* __restrict__ Wcat) {
    int gid = blockIdx.x * 256 + threadIdx.x;
    if (gid >= 512 * 272) return;
    int r = gid / 272, c = gid - r * 272;
    float v = 0.0f;
    if (c < 198) v = Ww[r * 198 + c];
    else if (c < 268) v = Wr[r * 70 + (c - 198)];
    Wcat[gid] = v;
}

// Persistent single workgroup (round-5 structure: M cols 0-31 in 32 VGPRs, cols 32-63
// in ws_m float4 private slots; fp32 throughout the recurrence).
// Round-7 change: weight matvecs load float4 column-groups (coalesced 16B/lane) instead
// of scalar strided columns -> 4x fewer load instructions, 4x more bytes outstanding
// per issue slot (round-5 was L2-latency-exposed on ~250cyc round trips).
__global__ __launch_bounds__(1024)
void ntm_kernel(
    const float* __restrict__ pre,   // [TT][CC]
    const float* __restrict__ Wc,    // [128][512]
    const float* __restrict__ Wcat,  // [512][272] packed Ww|Wr
    const float* __restrict__ br,    // [70]
    const float* __restrict__ bw,    // [198]
    const float* __restrict__ Wo,    // [64][64]
    const float* __restrict__ bo,    // [64]
    float* __restrict__ out,
    float4* __restrict__ ws_m)       // [8][1024] private M cols 32..63
{
    __shared__ __align__(16) float sh_part[4096];     // A: 8x512 ; C: 8x272
    __shared__ __align__(16) float sh_h[CC];
    __shared__ __align__(16) float sh_kw[MM];
    __shared__ __align__(16) float sh_kr[MM];
    __shared__ __align__(16) float sh_e[MM];
    __shared__ __align__(16) float sh_a[MM];
    __shared__ __align__(16) float sh_scal[16];
    __shared__ __align__(16) float sh_evbuf[NN];
    __shared__ __align__(16) float sh_wpbuf[NN];
    __shared__ __align__(16) float red[4][16];
    __shared__ __align__(16) float wmat[16][MM];
    __shared__ __align__(16) float sh_r[MM];
    __shared__ __align__(16) float sh_Wo[MM * LL];
    __shared__ __align__(16) float sh_bo[LL];
    __shared__ __align__(16) float sh_bw[200];
    __shared__ __align__(16) float sh_br[72];
    __shared__ __align__(16) float sh_pren[CC];       // prefetched pre[t+1]

    const int tid  = threadIdx.x;
    const int lane = tid & 63;
    const int wv   = tid >> 6;

    // ---- preload constants into LDS, init state ----
    for (int i = tid; i < MM * LL; i += NN) sh_Wo[i] = Wo[i];
    if (tid < LL)  sh_bo[tid] = bo[tid];
    if (tid < 198) sh_bw[tid] = bw[tid];
    if (tid < 70)  sh_br[tid] = br[tid];
    if (tid < MM)  sh_r[tid] = 1e-6f;
    if (tid < CC)  sh_pren[tid] = pre[tid];

    float Mlo[32];
    #pragma unroll
    for (int j = 0; j < 32; ++j) Mlo[j] = 1e-6f;
    float4 mh[8];
    #pragma unroll
    for (int k = 0; k < 8; ++k) {
        mh[k] = make_float4(1e-6f, 1e-6f, 1e-6f, 1e-6f);
        ws_m[k * NN + tid] = mh[k];
    }
    float rown = sqrtf(64.0f * 1e-12f);
    float wwprev = (tid == NN / 2) ? 1.0f : 0.0f;
    float rwprev = wwprev;
    __syncthreads();

    for (int t = 0; t < TT; ++t) {
        // ===== A: h-partials, float4 col-groups. thread=(g:128 col-groups, q:8 row-chunks) =====
        {
            int g = tid & 127, q = tid >> 7;          // cols 4g..4g+3, rows 8q..8q+7 of Wc2
            const float4* wbase = (const float4*)(Wc + (64 + q * 8) * CC) + g;
            float4 acc = make_float4(0.0f, 0.0f, 0.0f, 0.0f);
            #pragma unroll
            for (int i = 0; i < 8; ++i) {
                float rv = sh_r[q * 8 + i];
                float4 w = wbase[i * 128];            // next row: +512 floats = +128 float4
                acc.x += rv * w.x; acc.y += rv * w.y;
                acc.z += rv * w.z; acc.w += rv * w.w;
            }
            ((float4*)sh_part)[q * 128 + g] = acc;    // sh_part[q*512 + 4g]
        }
        __syncthreads();  // 1
        // ===== B: h = tanh(pre + 8 partials) =====
        if (tid < CC) {
            float p0 = sh_part[tid]          + sh_part[512 + tid];
            float p1 = sh_part[1024 + tid]   + sh_part[1536 + tid];
            float p2 = sh_part[2048 + tid]   + sh_part[2560 + tid];
            float p3 = sh_part[3072 + tid]   + sh_part[3584 + tid];
            float v = sh_pren[tid] + ((p0 + p1) + (p2 + p3));
            sh_h[tid] = tanh_f(v);
        }
        __syncthreads();  // 2
        // ===== C: ow/orr partials, float4 col-groups of Wcat. 544 threads =====
        if (tid < 544) {
            int g = tid % 68, q = tid / 68;           // cols 4g..4g+3, rows 64q..64q+63
            const float4* wbase = (const float4*)(Wcat + (q * 64) * 272) + g;
            float4 acc = make_float4(0.0f, 0.0f, 0.0f, 0.0f);
            #pragma unroll 8
            for (int i = 0; i < 64; ++i) {
                float hv = sh_h[q * 64 + i];
                float4 w = wbase[i * 68];             // next row: +272 floats = +68 float4
                acc.x += hv * w.x; acc.y += hv * w.y;
                acc.z += hv * w.z; acc.w += hv * w.w;
            }
            ((float4*)sh_part)[q * 68 + g] = acc;     // sh_part[q*272 + 4g]
        }
        __syncthreads();  // 3
        // ===== D: head transforms, ow folded inline from 8 partials (+ pre prefetch) =====
        #define OWV(c) ( (((sh_part[(c)] + sh_part[272 + (c)]) + (sh_part[544 + (c)] + sh_part[816 + (c)])) \
                        + ((sh_part[1088 + (c)] + sh_part[1360 + (c)]) + (sh_part[1632 + (c)] + sh_part[1904 + (c)]))) \
                        + ((c) < 198 ? sh_bw[(c)] : sh_br[(c) - 198]) )
        if (wv == 0) {
            float v = tanh_f(OWV(lane));
            sh_kw[lane] = v;
            float s2 = v * v;
            #pragma unroll
            for (int m = 1; m < 64; m <<= 1) s2 += __shfl_xor(s2, m, 64);
            if (lane == 0) sh_scal[6] = sqrtf(s2);
        } else if (wv == 1) {
            float v = tanh_f(OWV(198 + lane));
            sh_kr[lane] = v;
            float s2 = v * v;
            #pragma unroll
            for (int m = 1; m < 64; m <<= 1) s2 += __shfl_xor(s2, m, 64);
            if (lane == 0) sh_scal[14] = sqrtf(s2);
        } else if (wv == 2) {
            sh_e[lane] = sigmoid_f(OWV(70 + lane));
        } else if (wv == 3) {
            float v = tanh_f(OWV(134 + lane));
            sh_a[lane] = v;
            out[OFF_A + t * MM + lane] = v;
        } else if (wv == 4) {
            if (lane == 0) {
                sh_scal[0] = softplus_f(OWV(64));
                sh_scal[1] = sigmoid_f(OWV(65));
                float x0 = OWV(66), x1 = OWV(67), x2 = OWV(68);
                float mx = fmaxf(x0, fmaxf(x1, x2));
                float e0 = __expf(x0 - mx), e1 = __expf(x1 - mx), e2 = __expf(x2 - mx);
                float ss = e0 + e1 + e2;
                sh_scal[2] = e0 / ss; sh_scal[3] = e1 / ss; sh_scal[4] = e2 / ss;
                sh_scal[5] = 1.0f + softplus_f(OWV(69));
            }
        } else if (wv == 5) {
            if (lane == 0) {
                sh_scal[8] = softplus_f(OWV(198 + 64));
                sh_scal[9] = sigmoid_f(OWV(198 + 65));
                float x0 = OWV(198 + 66), x1 = OWV(198 + 67), x2 = OWV(198 + 68);
                float mx = fmaxf(x0, fmaxf(x1, x2));
                float e0 = __expf(x0 - mx), e1 = __expf(x1 - mx), e2 = __expf(x2 - mx);
                float ss = e0 + e1 + e2;
                sh_scal[10] = e0 / ss; sh_scal[11] = e1 / ss; sh_scal[12] = e2 / ss;
                sh_scal[13] = 1.0f + softplus_f(OWV(198 + 69));
            }
        } else if (wv >= 6 && wv < 14) {     // prefetch pre[t+1] into LDS (512 idle threads)
            if (t + 1 < TT) sh_pren[tid - 384] = pre[(t + 1) * CC + (tid - 384)];
        }
        #undef OWV
        __syncthreads();  // 4

        // ===== E: write-head dot + ev ===== (round-5 verbatim)
        float betaW = sh_scal[0], gW = sh_scal[1];
        float s0W = sh_scal[2], s1W = sh_scal[3], s2W = sh_scal[4];
        float gamW = sh_scal[5], knW = sh_scal[6];
        {
            #pragma unroll
            for (int k = 0; k < 8; ++k) mh[k] = ws_m[k * NN + tid];
            const float4* k4 = (const float4*)sh_kw;
            float d0 = 0.0f, d1 = 0.0f, d2 = 0.0f, d3 = 0.0f;
            #pragma unroll
            for (int j4 = 0; j4 < 8; ++j4) {
                float4 k = k4[j4];
                d0 += Mlo[4*j4]   * k.x;
                d1 += Mlo[4*j4+1] * k.y;
                d2 += Mlo[4*j4+2] * k.z;
                d3 += Mlo[4*j4+3] * k.w;
            }
            #pragma unroll
            for (int k8 = 0; k8 < 8; ++k8) {
                float4 k = k4[8 + k8];
                d0 += mh[k8].x * k.x;
                d1 += mh[k8].y * k.y;
                d2 += mh[k8].z * k.z;
                d3 += mh[k8].w * k.w;
            }
            float dot = (d0 + d1) + (d2 + d3);
            float sim = dot / (rown * knW + EPSF);
            float ev = __expf(betaW * sim);
            sh_evbuf[tid] = ev;
            sh_wpbuf[tid] = wwprev;
            float s = ev;
            #pragma unroll
            for (int m = 1; m < 64; m <<= 1) s += __shfl_xor(s, m, 64);
            if (lane == 0) red[0][wv] = s;
        }
        __syncthreads();  // 5
        // ===== F: conv + sharpen (write) =====
        float wshW;
        {
            const float4* rp = (const float4*)red[0];
            float Sev = 0.0f;
            #pragma unroll
            for (int w4 = 0; w4 < 4; ++w4) { float4 p = rp[w4]; Sev += p.x + p.y + p.z + p.w; }
            int tm1 = (tid + NN - 1) & (NN - 1), tp1 = (tid + 1) & (NN - 1);
            float cEV = s0W * sh_evbuf[tm1] + s1W * sh_evbuf[tid] + s2W * sh_evbuf[tp1];
            float cWP = s0W * sh_wpbuf[tm1] + s1W * sh_wpbuf[tid] + s2W * sh_wpbuf[tp1];
            float ws = (gW / Sev) * cEV + (1.0f - gW) * cWP;
            wshW = pow_f(ws, gamW);
            float s = wshW;
            #pragma unroll
            for (int m = 1; m < 64; m <<= 1) s += __shfl_xor(s, m, 64);
            if (lane == 0) red[1][wv] = s;
        }
        __syncthreads();  // 6
        // ===== G: normalize wwn; M update + norm =====
        {
            const float4* rp = (const float4*)red[1];
            float Swsh = 0.0f;
            #pragma unroll
            for (int w4 = 0; w4 < 4; ++w4) { float4 p = rp[w4]; Swsh += p.x + p.y + p.z + p.w; }
            float wwn = wshW / (Swsh + EPSF);
            out[OFF_WW + t * NN + tid] = wwn;
            wwprev = wwn;
            const float4* e4p = (const float4*)sh_e;
            const float4* a4p = (const float4*)sh_a;
            float n0 = 0.0f, n1 = 0.0f, n2 = 0.0f, n3 = 0.0f;
            #pragma unroll
            for (int j4 = 0; j4 < 8; ++j4) {
                float4 e = e4p[j4], a = a4p[j4];
                float m0 = Mlo[4*j4]   * (1.0f - wwn * e.x) + wwn * a.x;
                float m1 = Mlo[4*j4+1] * (1.0f - wwn * e.y) + wwn * a.y;
                float m2 = Mlo[4*j4+2] * (1.0f - wwn * e.z) + wwn * a.z;
                float m3 = Mlo[4*j4+3] * (1.0f - wwn * e.w) + wwn * a.w;
                Mlo[4*j4] = m0; Mlo[4*j4+1] = m1; Mlo[4*j4+2] = m2; Mlo[4*j4+3] = m3;
                n0 += m0 * m0; n1 += m1 * m1; n2 += m2 * m2; n3 += m3 * m3;
            }
            #pragma unroll
            for (int k = 0; k < 8; ++k) {
                float4 e = e4p[8 + k], a = a4p[8 + k];
                float4 m = mh[k];
                m.x = m.x * (1.0f - wwn * e.x) + wwn * a.x;
                m.y = m.y * (1.0f - wwn * e.y) + wwn * a.y;
                m.z = m.z * (1.0f - wwn * e.z) + wwn * a.z;
                m.w = m.w * (1.0f - wwn * e.w) + wwn * a.w;
                mh[k] = m;
                ws_m[k * NN + tid] = m;
                n0 += m.x * m.x; n1 += m.y * m.y; n2 += m.z * m.z; n3 += m.w * m.w;
            }
            rown = sqrtf((n0 + n1) + (n2 + n3));
        }

        // ===== H: read-head dot + ev =====
        float betaR = sh_scal[8], gR = sh_scal[9];
        float s0R = sh_scal[10], s1R = sh_scal[11], s2R = sh_scal[12];
        float gamR = sh_scal[13], knR = sh_scal[14];
        {
            const float4* k4 = (const float4*)sh_kr;
            float d0 = 0.0f, d1 = 0.0f, d2 = 0.0f, d3 = 0.0f;
            #pragma unroll
            for (int j4 = 0; j4 < 8; ++j4) {
                float4 k = k4[j4];
                d0 += Mlo[4*j4]   * k.x;
                d1 += Mlo[4*j4+1] * k.y;
                d2 += Mlo[4*j4+2] * k.z;
                d3 += Mlo[4*j4+3] * k.w;
            }
            #pragma unroll
            for (int k8 = 0; k8 < 8; ++k8) {
                float4 k = k4[8 + k8];
                d0 += mh[k8].x * k.x;
                d1 += mh[k8].y * k.y;
                d2 += mh[k8].z * k.z;
                d3 += mh[k8].w * k.w;
            }
            float dot = (d0 + d1) + (d2 + d3);
            float sim = dot / (rown * knR + EPSF);
            float ev = __expf(betaR * sim);
            sh_evbuf[tid] = ev;
            sh_wpbuf[tid] = rwprev;
            float s = ev;
            #pragma unroll
            for (int m = 1; m < 64; m <<= 1) s += __shfl_xor(s, m, 64);
            if (lane == 0) red[2][wv] = s;
        }
        __syncthreads();  // 7
        // ===== I: conv + sharpen (read); transpose partials =====
        float wshR;
        {
            const float4* rp = (const float4*)red[2];
            float Sev = 0.0f;
            #pragma unroll
            for (int w4 = 0; w4 < 4; ++w4) { float4 p = rp[w4]; Sev += p.x + p.y + p.z + p.w; }
            int tm1 = (tid + NN - 1) & (NN - 1), tp1 = (tid + 1) & (NN - 1);
            float cEV = s0R * sh_evbuf[tm1] + s1R * sh_evbuf[tid] + s2R * sh_evbuf[tp1];
            float cWP = s0R * sh_wpbuf[tm1] + s1R * sh_wpbuf[tid] + s2R * sh_wpbuf[tp1];
            float ws = (gR / Sev) * cEV + (1.0f - gR) * cWP;
            wshR = pow_f(ws, gamR);
            float s = wshR;
            #pragma unroll
            for (int m = 1; m < 64; m <<= 1) s += __shfl_xor(s, m, 64);
            if (lane == 0) red[3][wv] = s;
            #pragma unroll
            for (int chunk = 0; chunk < 4; ++chunk) {
                const int cb = chunk * 16;
                float v[16];
                if (chunk < 2) {
                    #pragma unroll
                    for (int i = 0; i < 16; ++i) v[i] = wshR * Mlo[chunk * 16 + i];
                } else {
                    #pragma unroll
                    for (int k = 0; k < 4; ++k) {
                        float4 m = mh[(chunk - 2) * 4 + k];
                        v[4*k]   = wshR * m.x;
                        v[4*k+1] = wshR * m.y;
                        v[4*k+2] = wshR * m.z;
                        v[4*k+3] = wshR * m.w;
                    }
                }
                #pragma unroll
                for (int st = 0; st < 4; ++st) {
                    const int m = 1 << st;
                    const int hs = 8 >> st;
                    bool hi = (lane & m) != 0;
                    #pragma unroll
                    for (int i = 0; i < 8; ++i) {
                        if (i < hs) {
                            float send = hi ? v[i] : v[i + hs];
                            float recv = __shfl_xor(send, m, 64);
                            float keep = hi ? v[i + hs] : v[i];
                            v[i] = keep + recv;
                        }
                    }
                }
                float v0 = v[0];
                v0 += __shfl_xor(v0, 16, 64);
                v0 += __shfl_xor(v0, 32, 64);
                if (lane < 16) wmat[wv][cb + bitrev4(lane)] = v0;
            }
        }
        __syncthreads();  // 8
        // ===== J: normalize rwn + finalize =====
        {
            const float4* rp = (const float4*)red[3];
            float Swsh = 0.0f;
            #pragma unroll
            for (int w4 = 0; w4 < 4; ++w4) { float4 p = rp[w4]; Swsh += p.x + p.y + p.z + p.w; }
            float inv = 1.0f / (Swsh + EPSF);
            float rwn = wshR * inv;
            out[OFF_RW + t * NN + tid] = rwn;
            rwprev = rwn;
            if (tid < MM) {
                float rv = 0.0f;
                #pragma unroll
                for (int w = 0; w < 16; ++w) rv += wmat[w][tid];
                rv *= inv;
                sh_r[tid] = rv;
                out[OFF_R + t * MM + tid] = rv;
            }
        }
        __syncthreads();  // 9
        // ===== K: output projection =====
        if (tid < LL) {
            const float4* r4p = (const float4*)sh_r;
            float a0 = 0.0f, a1 = 0.0f;
            #pragma unroll
            for (int i4 = 0; i4 < 16; ++i4) {
                float4 r = r4p[i4];
                a0 += r.x * sh_Wo[(4*i4) * LL + tid]   + r.y * sh_Wo[(4*i4+1) * LL + tid];
                a1 += r.z * sh_Wo[(4*i4+2) * LL + tid] + r.w * sh_Wo[(4*i4+3) * LL + tid];
            }
            float acc = sh_bo[tid] + a0 + a1;
            out[OFF_SEQ + t * LL + tid] = fminf(fmaxf(acc, 0.0f), 1.0f);
        }
        // no barrier: next phase A reads only sh_r (stable until next J)
    }
}

extern "C" void kernel_launch(void* const* d_in, const int* in_sizes, int n_in,
                              void* d_out, int out_size, void* d_ws, size_t ws_size,
                              hipStream_t stream) {
    const float* seq = (const float*)d_in[0];
    const float* Wc  = (const float*)d_in[1];
    const float* bc  = (const float*)d_in[2];
    const float* Wr  = (const float*)d_in[3];
    const float* br  = (const float*)d_in[4];
    const float* Ww  = (const float*)d_in[5];
    const float* bw  = (const float*)d_in[6];
    const float* Wo  = (const float*)d_in[7];
    const float* bo  = (const float*)d_in[8];
    float* out = (float*)d_out;

    float* wsf  = (float*)d_ws;
    float* pre  = wsf + WSF_PRE;
    float4* ws_m = (float4*)(wsf + WSF_M);
    float* Wcat = wsf + WSF_WCAT;

    pre_kernel<<<(TT * CC) / 256, 256, 0, stream>>>(seq, Wc, bc, pre);
    pack_kernel<<<(512 * 272 + 255) / 256, 256, 0, stream>>>(Ww, Wr, Wcat);
    ntm_kernel<<<1, 1024, 0, stream>>>(pre, Wc, Wcat, br, bw, Wo, bo, out, ws_m);
}